// Round 4
// baseline (589.696 us; speedup 1.0000x reference)
//
#include <hip/hip_runtime.h>
#include <hip/hip_bf16.h>

#define NT 65536
#define MD 1024
#define NE 64

typedef __attribute__((ext_vector_type(8))) short s8v;   // 8 bf16 = 4 VGPR
typedef __attribute__((ext_vector_type(4))) float f4v;   // MFMA accumulator

// RNE f32 -> bf16 bits
static __device__ inline short bf16bits(float v) {
    __hip_bfloat16 b = __float2bfloat16(v);
    return *reinterpret_cast<short*>(&b);
}
static __device__ inline float bf16tof(short s) {
    return __uint_as_float(((unsigned)(unsigned short)s) << 16);
}

// ---------------------------------------------------------------------------
// Kernel 0: split wg into hi/lo bf16, laid out in MFMA B-fragment order:
//   flat[(kc*4 + tile)*64 + lane][j] = wg[tile*16 + (lane&15)][kc*32 + (lane>>4)*8 + j]
// ---------------------------------------------------------------------------
__global__ __launch_bounds__(256) void wsplit_kernel(
    const float* __restrict__ wg, short* __restrict__ wgh, short* __restrict__ wgl)
{
    const int gid = blockIdx.x * 256 + threadIdx.x;  // 0..8191
    const int lane = gid & 63;
    const int tile = (gid >> 6) & 3;
    const int kc = gid >> 8;
    const int n = tile * 16 + (lane & 15);
    const int k0 = kc * 32 + (lane >> 4) * 8;
    const float* src = wg + (size_t)n * MD + k0;
    short h[8], l[8];
#pragma unroll
    for (int j = 0; j < 8; ++j) {
        float v = src[j];
        short hb = bf16bits(v);
        h[j] = hb;
        l[j] = bf16bits(v - bf16tof(hb));
    }
    s8v hv, lv;
#pragma unroll
    for (int j = 0; j < 8; ++j) { hv[j] = h[j]; lv[j] = l[j]; }
    *(s8v*)(wgh + (size_t)gid * 8) = hv;
    *(s8v*)(wgl + (size_t)gid * 8) = lv;
}

// ---------------------------------------------------------------------------
// Kernel 1: MFMA gating GEMM (bf16 split: xh*wh + xl*wh + xh*wl) + argmax +
// top-2 gap flag + softmax + me accumulation. 64 tokens/block, 4 waves, each
// wave = 16 tokens x 64 experts (4 n-tiles of 16x16x32). NO LDS in K-loop.
// ---------------------------------------------------------------------------
__global__ __launch_bounds__(256) void gate_mfma(
    const float* __restrict__ x, const short* __restrict__ wgh,
    const short* __restrict__ wgl, float* __restrict__ out,
    unsigned char* __restrict__ am8, unsigned char* __restrict__ flag,
    float* __restrict__ me)
{
    __shared__ float lt[64 * 65 + 64];   // logits tile + inv[]
    const int tid = threadIdx.x;
    const int lane = tid & 63;
    const int wv = tid >> 6;
    const int t0 = blockIdx.x * 64;

    const int arow = t0 + wv * 16 + (lane & 15);
    const float* xr = x + (size_t)arow * MD + (lane >> 4) * 8;
    const short* bh_base = wgh + lane * 8;
    const short* bl_base = wgl + lane * 8;

    f4v acc[4] = {f4v{0,0,0,0}, f4v{0,0,0,0}, f4v{0,0,0,0}, f4v{0,0,0,0}};

#pragma unroll 2
    for (int kc = 0; kc < 32; ++kc) {
        float4 a0 = *(const float4*)(xr + kc * 32);
        float4 a1 = *(const float4*)(xr + kc * 32 + 4);
        float av[8] = {a0.x, a0.y, a0.z, a0.w, a1.x, a1.y, a1.z, a1.w};
        s8v ah, al;
#pragma unroll
        for (int j = 0; j < 8; ++j) {
            short hb = bf16bits(av[j]);
            ah[j] = hb;
            al[j] = bf16bits(av[j] - bf16tof(hb));
        }
        const short* bp = bh_base + (size_t)kc * 2048;
        const short* lp = bl_base + (size_t)kc * 2048;
#pragma unroll
        for (int t = 0; t < 4; ++t) {
            s8v bh = *(const s8v*)(bp + t * 512);
            s8v bl = *(const s8v*)(lp + t * 512);
            acc[t] = __builtin_amdgcn_mfma_f32_16x16x32_bf16(ah, bh, acc[t], 0, 0, 0);
            acc[t] = __builtin_amdgcn_mfma_f32_16x16x32_bf16(al, bh, acc[t], 0, 0, 0);
            acc[t] = __builtin_amdgcn_mfma_f32_16x16x32_bf16(ah, bl, acc[t], 0, 0, 0);
        }
    }

    // C/D layout (m89-verified): col = lane&15, row = (lane>>4)*4 + reg
#pragma unroll
    for (int t = 0; t < 4; ++t)
#pragma unroll
        for (int r = 0; r < 4; ++r)
            lt[(wv * 16 + (lane >> 4) * 4 + r) * 65 + t * 16 + (lane & 15)] = acc[t][r];
    __syncthreads();

    float* inv = lt + 4160;
    if (tid < 64) {
        const int t = tid;
        float m = -1e30f, m2 = -1e30f; int am = 0;
        for (int e = 0; e < NE; ++e) {
            float v = lt[t * 65 + e];
            if (v > m) { m2 = m; m = v; am = e; }     // first-max like jnp.argmax
            else if (v > m2) m2 = v;
        }
        float s = 0.f;
        for (int e = 0; e < NE; ++e) {
            float ev = __expf(lt[t * 65 + e] - m);
            lt[t * 65 + e] = ev;
            s += ev;
        }
        float g = 1.0f / s;
        const int gt = t0 + t;
        out[2 + 2 * NT + gt] = g;                     // gates1_s (split precision)
        am8[gt] = (unsigned char)am;
        flag[gt] = (m - m2 < 0.01f) ? 1 : 0;          // top-2 gap guard
        inv[t] = g;
    }
    __syncthreads();

    if (tid < NE) {
        const int e = tid;
        float s = 0.f;
        for (int t = 0; t < 64; ++t) s += lt[t * 65 + e] * inv[t];
        atomicAdd(&me[e], s);
    }
}

// ---------------------------------------------------------------------------
// Kernel 2: rescue — exact fp32 recompute of flagged (near-tie) tokens.
// ---------------------------------------------------------------------------
__global__ __launch_bounds__(256) void rescue_kernel(
    const float* __restrict__ x, const float* __restrict__ wg,
    const unsigned char* __restrict__ flag, unsigned char* __restrict__ am8,
    float* __restrict__ out)
{
    __shared__ float part[256];
    __shared__ float lg[64];
    __shared__ int list[256];
    __shared__ int cnt;
    const int tid = threadIdx.x;
    const int base = blockIdx.x * 256;

    if (tid == 0) cnt = 0;
    __syncthreads();
    if (flag[base + tid]) { int p = atomicAdd(&cnt, 1); list[p] = base + tid; }
    __syncthreads();
    const int n = cnt;

    const int e = tid & 63, c = tid >> 6;
    for (int i = 0; i < n; ++i) {
        const int t = list[i];
        const float4* xr = (const float4*)(x + (size_t)t * MD + c * 256);
        const float4* wr = (const float4*)(wg + (size_t)e * MD + c * 256);
        float s = 0.f;
#pragma unroll 4
        for (int j = 0; j < 64; ++j) {
            float4 xa = xr[j], wa = wr[j];
            s += xa.x * wa.x + xa.y * wa.y + xa.z * wa.z + xa.w * wa.w;
        }
        part[tid] = s;
        __syncthreads();
        if (tid < 64) lg[tid] = part[tid] + part[tid + 64] + part[tid + 128] + part[tid + 192];
        __syncthreads();
        if (tid == 0) {
            float m = -1e30f; int am = 0;
            for (int q = 0; q < NE; ++q) { float v = lg[q]; if (v > m) { m = v; am = q; } }
            float ssum = 0.f;
            for (int q = 0; q < NE; ++q) ssum += __expf(lg[q] - m);
            am8[t] = (unsigned char)am;
            out[2 + 2 * NT + t] = 1.0f / ssum;
        }
        __syncthreads();
    }
}

// ---------------------------------------------------------------------------
// Kernel 3: ballot ranks + per-64-token-group histogram + indices output.
// ---------------------------------------------------------------------------
__global__ __launch_bounds__(256) void rankhist_kernel(
    const unsigned char* __restrict__ am8, float* __restrict__ out,
    unsigned* __restrict__ packed, int* __restrict__ hist)
{
    const int t = blockIdx.x * 256 + threadIdx.x;
    const int lane = t & 63;
    const int am = am8[t];
    out[1 + t] = (float)am;
    const unsigned long long below = (1ull << lane) - 1ull;
    int rank = 0, mycnt = 0;
    for (int e = 0; e < NE; ++e) {
        unsigned long long msk = __ballot(am == e);
        if (lane == e) mycnt = (int)__popcll(msk);
        if (am == e)   rank  = (int)__popcll(msk & below);
    }
    packed[t] = (unsigned)am | ((unsigned)rank << 8);
    hist[(t >> 6) * NE + lane] = mycnt;
}

// ---------------------------------------------------------------------------
// Kernel 4: per-expert exclusive scan over 1024 group histograms (+ ce).
// ---------------------------------------------------------------------------
__global__ __launch_bounds__(256) void scan_kernel(
    int* __restrict__ hist_ws, float* __restrict__ ce)
{
    const int e = blockIdx.x;
    const int tid = threadIdx.x;
    const int lane = tid & 63, wave = tid >> 6;
    __shared__ int wtot[4];

    int h[4];
#pragma unroll
    for (int j = 0; j < 4; ++j) h[j] = hist_ws[(tid * 4 + j) * NE + e];
    int s = h[0] + h[1] + h[2] + h[3];

    int scan = s;
#pragma unroll
    for (int d = 1; d < 64; d <<= 1) {
        int o = __shfl_up(scan, d, 64);
        if (lane >= d) scan += o;
    }
    if (lane == 63) wtot[wave] = scan;
    __syncthreads();
    int wpre = 0;
#pragma unroll
    for (int w = 0; w < 4; ++w)
        if (w < wave) wpre += wtot[w];

    int run = wpre + scan - s;
#pragma unroll
    for (int j = 0; j < 4; ++j) {
        hist_ws[(tid * 4 + j) * NE + e] = run;
        run += h[j];
    }
    if (tid == 255) ce[e] = (float)run;
}

// ---------------------------------------------------------------------------
// Kernel 5: locations1_s = group offset + in-group rank.
// ---------------------------------------------------------------------------
__global__ __launch_bounds__(256) void emit_kernel(
    const unsigned* __restrict__ packed, const int* __restrict__ offs,
    float* __restrict__ out)
{
    const int i = blockIdx.x * 256 + threadIdx.x;
    const unsigned p = packed[i];
    const int am = (int)(p & 63u);
    const int rank = (int)(p >> 8);
    out[2 + NT + i] = (float)(offs[(i >> 6) * NE + am] + rank);
}

// ---------------------------------------------------------------------------
// Kernel 6: l_aux + scalars.
// ---------------------------------------------------------------------------
__global__ void finalize_kernel(const float* __restrict__ me,
                                const float* __restrict__ ce,
                                float* __restrict__ out)
{
    int tid = threadIdx.x;
    float v = me[tid] * ce[tid];
#pragma unroll
    for (int d = 32; d > 0; d >>= 1) v += __shfl_down(v, d, 64);
    if (tid == 0) {
        out[0] = v * (float)((double)NE / ((double)NT * (double)NT));
        out[1 + NT] = 1024.0f;      // capacity
        out[2 + 3 * NT] = 64.0f;    // E
    }
}

extern "C" void kernel_launch(void* const* d_in, const int* in_sizes, int n_in,
                              void* d_out, int out_size, void* d_ws, size_t ws_size,
                              hipStream_t stream)
{
    const float* x  = (const float*)d_in[0];
    const float* wg = (const float*)d_in[1];
    float* out = (float*)d_out;

    char* ws = (char*)d_ws;
    short* wgh = (short*)ws;                                  // 128 KB
    short* wgl = (short*)(ws + 131072);                       // 128 KB
    unsigned char* am8  = (unsigned char*)(ws + 262144);      // 64 KB
    unsigned char* flag = (unsigned char*)(ws + 327680);      // 64 KB
    unsigned* packed = (unsigned*)(ws + 393216);              // 256 KB
    int* hist = (int*)(ws + 655360);                          // 256 KB
    float* me = (float*)(ws + 917504);
    float* ce = me + NE;

    hipMemsetAsync(me, 0, NE * sizeof(float), stream);
    wsplit_kernel<<<32, 256, 0, stream>>>(wg, wgh, wgl);
    gate_mfma<<<NT / 64, 256, 0, stream>>>(x, wgh, wgl, out, am8, flag, me);
    rescue_kernel<<<NT / 256, 256, 0, stream>>>(x, wg, flag, am8, out);
    rankhist_kernel<<<NT / 256, 256, 0, stream>>>(am8, out, packed, hist);
    scan_kernel<<<NE, 256, 0, stream>>>(hist, ce);
    emit_kernel<<<NT / 256, 256, 0, stream>>>(packed, hist, out);
    finalize_kernel<<<1, 64, 0, stream>>>(me, ce, out);
}